// Round 6
// baseline (107.903 us; speedup 1.0000x reference)
//
#include <hip/hip_runtime.h>

#define T_STEPS 1024
#define B_ELEMS 32768
#define K_SPLIT 2                 // time chunks (redundant warm-up compute)
#define NS (T_STEPS / K_SPLIT)    // 512 stored steps per chunk
#define STEP 0.5f

typedef float f32x4 __attribute__((ext_vector_type(4)));

__global__ __launch_bounds__(128) void seir_euler_kernel(
    const float* __restrict__ initial,   // (4, B)
    const float* __restrict__ beta,
    const float* __restrict__ gamma,
    const float* __restrict__ sigma,
    f32x4* __restrict__ out)             // (T*B) rows of 4 floats
{
    constexpr int B = B_ELEMS;
    const int b = blockIdx.x * 64 + threadIdx.x;   // lane-contiguous batch idx
    const int c = threadIdx.y;                     // time chunk 0..1

    const float bb = beta[0];
    const float gg = gamma[0];
    const float ss = sigma[0];

    float S = initial[0 * B + b];
    float E = initial[1 * B + b];
    float I = initial[2 * B + b];
    float R = initial[3 * B + b];

    // Warm-up: advance serially (bit-exact, same op order) to this chunk's start.
    const int start = c * NS;
    for (int n = 0; n < start; ++n) {
        float bSI = bb * S * I;
        float sE  = ss * E;
        float gI  = gg * I;
        float Sn = S - bSI * STEP;
        float En = E + (bSI - sE) * STEP;
        float In = I + (sE - gI) * STEP;
        float Rn = R + gI * STEP;
        S = Sn; E = En; I = In; R = Rn;
    }

    // Stored phase: plain (L2-allocating) stores + 4 waves/CU so TLP covers
    // the store-retire latency — the fill kernel's proven operating point.
    size_t idx = (size_t)start * B + b;
    for (int n = 0; n < NS; ++n, idx += B) {
        f32x4 v = {S, E, I, R};
        out[idx] = v;
        float bSI = bb * S * I;
        float sE  = ss * E;
        float gI  = gg * I;
        float Sn = S - bSI * STEP;
        float En = E + (bSI - sE) * STEP;
        float In = I + (sE - gI) * STEP;
        float Rn = R + gI * STEP;
        S = Sn; E = En; I = In; R = Rn;
    }
}

extern "C" void kernel_launch(void* const* d_in, const int* in_sizes, int n_in,
                              void* d_out, int out_size, void* d_ws, size_t ws_size,
                              hipStream_t stream)
{
    const float* initial = (const float*)d_in[0];
    const float* beta    = (const float*)d_in[1];
    const float* gamma   = (const float*)d_in[2];
    const float* sigma   = (const float*)d_in[3];
    f32x4* out = (f32x4*)d_out;

    dim3 block(64, K_SPLIT);            // 2 waves/block: same b-range, 2 time chunks
    dim3 grid(B_ELEMS / 64);            // 512 blocks -> 1024 waves -> 4 waves/CU
    seir_euler_kernel<<<grid, block, 0, stream>>>(initial, beta, gamma, sigma, out);
}

// Round 7
// 93.560 us; speedup vs baseline: 1.1533x; 1.1533x over previous
//
#include <hip/hip_runtime.h>

#define T_STEPS 1024
#define B_ELEMS 32768
#define BATCH 8
#define STEP 0.5f

typedef float f32x4 __attribute__((ext_vector_type(4)));

__global__ __launch_bounds__(64) void seir_euler_kernel(
    const float* __restrict__ initial,   // (4, B)
    const float* __restrict__ beta,
    const float* __restrict__ gamma,
    const float* __restrict__ sigma,
    f32x4* __restrict__ out)             // (T*B) rows of 4 floats
{
    constexpr int B = B_ELEMS;
    const int b = blockIdx.x * 64 + threadIdx.x;

    const float bb = beta[0];
    const float gg = gamma[0];
    const float ss = sigma[0];

    float S = initial[0 * B + b];
    float E = initial[1 * B + b];
    float I = initial[2 * B + b];
    float R = initial[3 * B + b];

    // Compute-8-then-store-8: 8 fully independent store-data sets issued as a
    // back-to-back burst (fill-kernel-like), instead of dep-chain-paced
    // store-per-step. sched_barrier(0) pins the phase split so the scheduler
    // can't re-interleave stores into the compute chain.
    size_t idx = (size_t)b;
    for (int t = 0; t < T_STEPS; t += BATCH) {
        f32x4 buf[BATCH];
#pragma unroll
        for (int k = 0; k < BATCH; ++k) {
            f32x4 v = {S, E, I, R};
            buf[k] = v;
            float bSI = bb * S * I;
            float sE  = ss * E;
            float gI  = gg * I;
            float Sn = S - bSI * STEP;
            float En = E + (bSI - sE) * STEP;
            float In = I + (sE - gI) * STEP;
            float Rn = R + gI * STEP;
            S = Sn; E = En; I = In; R = Rn;
        }
        __builtin_amdgcn_sched_barrier(0);
#pragma unroll
        for (int k = 0; k < BATCH; ++k) {
            __builtin_nontemporal_store(buf[k], &out[idx]);
            idx += B;
        }
        __builtin_amdgcn_sched_barrier(0);
    }
}

extern "C" void kernel_launch(void* const* d_in, const int* in_sizes, int n_in,
                              void* d_out, int out_size, void* d_ws, size_t ws_size,
                              hipStream_t stream)
{
    const float* initial = (const float*)d_in[0];
    const float* beta    = (const float*)d_in[1];
    const float* gamma   = (const float*)d_in[2];
    const float* sigma   = (const float*)d_in[3];
    f32x4* out = (f32x4*)d_out;

    const int block = 64;                     // 512 waves -> 2 per CU, all CUs
    const int grid = B_ELEMS / block;         // 512 blocks
    seir_euler_kernel<<<grid, block, 0, stream>>>(initial, beta, gamma, sigma, out);
}